// Round 12
// baseline (82.268 us; speedup 1.0000x reference)
//
#include <hip/hip_runtime.h>

// Fused masked 3x3 conv x2 (MinkowskiConv stride-1 equivalent), fp32:
//   m   = float(mask)
//   h   = relu((conv3x3(x*m, w1) + b1) * m)
//   out = (conv3x3(h, w2) + b2) * m
// Round-11 structure (LDS-tiled, enc-sign mask folding, conflict-free conv2
// vertical register rolling, NON-TEMPORAL output stores) + conv1 processes
// h-point PAIRS with aligned float2 taps: halves conv1 iterations (the
// dominant VALU phase). Mask stays staged in s_hm — no global re-reads.

#define TB_W 128           // output tile width
#define TB_H 16            // output tile height
#define SX   136           // staged width:  TB_W + 8 (16B-aligned halo)
#define SY   20            // staged height: TB_H + 4
#define NV4  (SX / 4)      // 34 float4 per staged row
#define NSTG (SY * NV4)    // 680
#define HX   130           // h region width  (TB_W + 2)
#define HY   18            // h region height (TB_H + 2)
#define HP   (HX / 2)      // 65 h-pairs per row
#define NHP  (HY * HP)     // 1170

__global__ __launch_bounds__(256) void fused_mconv2(
    const float* __restrict__ x, const int* __restrict__ mask,
    const float* __restrict__ w1p, const float* __restrict__ b1p,
    const float* __restrict__ w2p, const float* __restrict__ b2p,
    float* __restrict__ out, int H, int W)
{
    __shared__ __align__(16) float s_xm[SY][SX];   // x*m over halo-2 region
    __shared__ __align__(16) float s_hm[SY][SX];   // stage: m; after conv1: enc(h,m)

    const int tid  = threadIdx.y * 64 + threadIdx.x;     // block (64,4)
    const int c0   = blockIdx.x * TB_W;
    const int row0 = blockIdx.y * TB_H;
    const size_t plane = (size_t)H * W;
    const float* xb = x    + (size_t)blockIdx.z * plane;
    const int*   mb = mask + (size_t)blockIdx.z * plane;
    float*       ob = out  + (size_t)blockIdx.z * plane;

    float W1[9], W2[9];
    #pragma unroll
    for (int i = 0; i < 9; ++i) { W1[i] = w1p[i]; W2[i] = w2p[i]; }
    const float B1 = b1p[0], B2 = b2p[0];

    // ---- stage: x*m and m, float4/int4 vector loads, origin (row0-2, c0-4) ----
    for (int idx = tid; idx < NSTG; idx += 256) {
        const int row  = idx / NV4;
        const int col4 = idx - row * NV4;
        const int r = row0 - 2 + row;
        const int c = c0 - 4 + (col4 << 2);
        float4 xm = make_float4(0.f, 0.f, 0.f, 0.f);
        float4 mm = make_float4(0.f, 0.f, 0.f, 0.f);
        if (r >= 0 && r < H && c >= 0 && c < W) {   // c%4==0, W%4==0 -> all-or-nothing
            const size_t g = (size_t)r * W + c;
            const float4 xv = *reinterpret_cast<const float4*>(xb + g);
            const int4   mi = *reinterpret_cast<const int4*>(mb + g);
            mm = make_float4((float)mi.x, (float)mi.y, (float)mi.z, (float)mi.w);
            xm = make_float4(xv.x * mm.x, xv.y * mm.y, xv.z * mm.z, xv.w * mm.w);
        }
        *reinterpret_cast<float4*>(&s_xm[row][col4 << 2]) = xm;
        *reinterpret_cast<float4*>(&s_hm[row][col4 << 2]) = mm;
    }
    __syncthreads();

    // ---- conv1 (PAIRS): enc = m ? relu(conv(x*m)+b1) : -1, 130x18 region ----
    // Pair h-cols (hc, hc+1); taps s_xm rows hrow..hrow+2, stage cols
    // hc+2..hc+5 = two aligned float2 per row. Own-point masks at s_hm
    // [hrow+1][hc+3 / hc+4]; same thread reads+overwrites them (no race).
    for (int idx = tid; idx < NHP; idx += 256) {
        const int hrow = idx / HP;
        const int hp   = idx - hrow * HP;
        const int hc   = hp << 1;
        float acc0 = B1, acc1 = B1;
        #pragma unroll
        for (int di = 0; di < 3; ++di) {
            const float2 A = *reinterpret_cast<const float2*>(&s_xm[hrow + di][hc + 2]);
            const float2 Bv = *reinterpret_cast<const float2*>(&s_xm[hrow + di][hc + 4]);
            acc0 += W1[di * 3] * A.x  + W1[di * 3 + 1] * A.y  + W1[di * 3 + 2] * Bv.x;
            acc1 += W1[di * 3] * A.y  + W1[di * 3 + 1] * Bv.x + W1[di * 3 + 2] * Bv.y;
        }
        const float m0 = s_hm[hrow + 1][hc + 3];
        const float m1 = s_hm[hrow + 1][hc + 4];
        const float h0 = acc0 > 0.f ? acc0 : 0.f;
        const float h1 = acc1 > 0.f ? acc1 : 0.f;
        s_hm[hrow + 1][hc + 3] = (m0 > 0.5f) ? h0 : -1.0f;
        s_hm[hrow + 1][hc + 4] = (m1 > 0.5f) ? h1 : -1.0f;
    }
    __syncthreads();

    // ---- conv2: column-per-lane register rolling, conflict-free reads ----
    {
        const int j     = tid & 127;        // output column
        const int strip = tid >> 7;         // 0..1
        const int i0    = strip * (TB_H / 2);
        float P = 0.f, Q = 0.f, cm = 0.f;
        #pragma unroll
        for (int t = 1; t <= TB_H / 2 + 2; ++t) {
            const int s = i0 + t;
            const float* rowp = &s_hm[s][0];
            const float t0 = rowp[j + 3];
            const float t1 = rowp[j + 4];
            const float t2 = rowp[j + 5];
            const float r0 = t0 > 0.f ? t0 : 0.f;
            const float r1 = t1 > 0.f ? t1 : 0.f;
            const float r2 = t2 > 0.f ? t2 : 0.f;
            const float d0 = W2[0] * r0 + W2[1] * r1 + W2[2] * r2;
            const float d1 = W2[3] * r0 + W2[4] * r1 + W2[5] * r2;
            const float d2 = W2[6] * r0 + W2[7] * r1 + W2[8] * r2;
            if (t >= 3) {
                const int i = s - 3;
                const float v = (cm >= 0.f) ? (Q + d2 + B2) : 0.f;
                __builtin_nontemporal_store(
                    v, ob + (size_t)(row0 + i) * W + (c0 + j));
            }
            Q  = P + d1;
            P  = d0;
            cm = t1;
        }
    }
}

extern "C" void kernel_launch(void* const* d_in, const int* in_sizes, int n_in,
                              void* d_out, int out_size, void* d_ws, size_t ws_size,
                              hipStream_t stream) {
    const float* x    = (const float*)d_in[0];
    const int*   mask = (const int*)  d_in[1];
    const float* w1   = (const float*)d_in[2];
    const float* b1   = (const float*)d_in[3];
    const float* w2   = (const float*)d_in[4];
    const float* b2   = (const float*)d_in[5];
    float*       out  = (float*)d_out;

    const int H = 2048, W = 2048;
    const int B = in_sizes[0] / (H * W);

    dim3 block(64, 4, 1);
    dim3 grid(W / TB_W, H / TB_H, B);   // 16 x 128 x 8
    hipLaunchKernelGGL(fused_mconv2, grid, block, 0, stream,
                       x, mask, w1, b1, w2, b2, out, H, W);
}